// Round 10
// baseline (268.081 us; speedup 1.0000x reference)
//
#include <hip/hip_runtime.h>
#include <stdint.h>

typedef unsigned int u32;
typedef unsigned short u16;
typedef __attribute__((ext_vector_type(8))) _Float16 f16x8;
typedef __attribute__((ext_vector_type(16))) float f32x16;

#define DEVI __device__ __forceinline__

// ---------------- numeric helpers ----------------
DEVI u16 f2h(float f) {  // f32 -> f16 RNE (v_cvt_f16_f32)
  _Float16 h = (_Float16)f;
  return __builtin_bit_cast(u16, h);
}

// ---------------- ws layout (bytes) ----------------
#define WS_E16 0             // f16 E, [1024 rows][512]
#define WS_WT (1u << 20)     // f16 W1^T, [512 ch][2048 k]
#define WS_A (3u << 20)      // f32 a = E@Wa
#define WS_C (5u << 20)      // f32 c = E@Wb

// ---------------- kernel 0: fused E->f16 + out-zeroing (blocks 0..511) and
//                  W1 (2048x512 f32) -> W16T (512x2048 f16) (blocks 512..767)
__global__ void k_cvt(const float* __restrict__ E, u16* __restrict__ E16,
                      const float* __restrict__ W1, u16* __restrict__ WT,
                      float* __restrict__ outz) {
  __shared__ float tile[64][65];
  if (blockIdx.x < 512) {
    int i = (blockIdx.x * blockDim.x + threadIdx.x) * 4;
    float4 v = *(const float4*)(E + i);
    ushort4 o;
    o.x = f2h(v.x); o.y = f2h(v.y); o.z = f2h(v.z); o.w = f2h(v.w);
    *(ushort4*)(E16 + i) = o;
    // fold output zeroing (atomic-combine target): 256 blocks x 1024 floats
    if (blockIdx.x < 256) {
      float4 z; z.x = 0.f; z.y = 0.f; z.z = 0.f; z.w = 0.f;
      *(float4*)(outz + (blockIdx.x * blockDim.x + threadIdx.x) * 4) = z;
    }
    return;
  }
  int bid = blockIdx.x - 512;
  int t = threadIdx.x;
  int kBase = (bid & 31) * 64;   // 32 k-tiles
  int chBase = (bid >> 5) * 64;  // 8 ch-tiles
  int lr = t >> 4, lc = (t & 15) * 4;
  for (int rr = 0; rr < 4; rr++) {
    int kr = lr + rr * 16;
    float4 v = *(const float4*)(W1 + (kBase + kr) * 512 + chBase + lc);
    tile[kr][lc] = v.x; tile[kr][lc + 1] = v.y;
    tile[kr][lc + 2] = v.z; tile[kr][lc + 3] = v.w;
  }
  __syncthreads();
  int ch = t >> 2, ks = (t & 3) * 16;
  u32 w[8];
  for (int u = 0; u < 8; u++) {
    u16 lo = f2h(tile[ks + 2 * u][ch]);
    u16 hi = f2h(tile[ks + 2 * u + 1][ch]);
    w[u] = (u32)lo | ((u32)hi << 16);
  }
  u16* dst = WT + (chBase + ch) * 2048 + kBase + ks;
  uint4 s0; s0.x = w[0]; s0.y = w[1]; s0.z = w[2]; s0.w = w[3];
  uint4 s1; s1.x = w[4]; s1.y = w[5]; s1.z = w[6]; s1.w = w[7];
  *(uint4*)(dst) = s0;
  *(uint4*)(dst + 8) = s1;
}

// ---------------- kernel 1: a = E@Wa, c = E@Wb (f16 MFMA) ----------------
__global__ __launch_bounds__(256, 4) void k_ac(const u16* __restrict__ E16,
                                               const u16* __restrict__ WT,
                                               float* __restrict__ Aw,
                                               float* __restrict__ Cw) {
  __shared__ __align__(16) char smem[16384];
  char* sA = smem;
  char* sB = smem + 8192;
  const int tid = threadIdx.x;
  const int lane = tid & 63, wid = tid >> 6;
  const int wr = wid >> 1, wcl = wid & 1;
  const int n = lane & 31, q = lane >> 5;
  const int rowBase = blockIdx.y * 128;
  const int chBase = blockIdx.x * 128;
  const int halfOff = (chBase >= 512) ? 512 : 0;
  const int chSrc0 = chBase - halfOff;
  f32x16 acc[2][2];
  for (int a = 0; a < 2; a++)
    for (int c = 0; c < 2; c++)
      for (int e = 0; e < 16; e++) acc[a][c][e] = 0.f;
  for (int kc = 0; kc < 16; kc++) {
    const int k0 = kc * 32;
    __syncthreads();
    for (int s2 = 0; s2 < 2; s2++) {
      int s = tid * 2 + s2;
      int row = s >> 2, pg = s & 3, lg = pg ^ ((row >> 1) & 3);
      *(uint4*)(sA + row * 64 + lg * 16) =
          *(const uint4*)(E16 + (rowBase + row) * 512 + k0 + pg * 8);
      *(uint4*)(sB + row * 64 + lg * 16) =
          *(const uint4*)(WT + (chSrc0 + row) * 2048 + halfOff + k0 + pg * 8);
    }
    __syncthreads();
    for (int ks = 0; ks < 2; ks++) {
      int kg = ks * 2 + q;
      f16x8 af[2], bfr[2];
      for (int rb = 0; rb < 2; rb++) {
        int row = wr * 64 + rb * 32 + n;
        af[rb] = *(const f16x8*)(sA + row * 64 + ((kg ^ ((row >> 1) & 3)) * 16));
      }
      for (int cb = 0; cb < 2; cb++) {
        int ch = wcl * 64 + cb * 32 + n;
        bfr[cb] = *(const f16x8*)(sB + ch * 64 + ((kg ^ ((ch >> 1) & 3)) * 16));
      }
      for (int rb = 0; rb < 2; rb++)
        for (int cb = 0; cb < 2; cb++)
          acc[rb][cb] = __builtin_amdgcn_mfma_f32_32x32x16_f16(af[rb], bfr[cb],
                                                              acc[rb][cb], 0, 0, 0);
    }
  }
  for (int rb = 0; rb < 2; rb++)
    for (int cb = 0; cb < 2; cb++)
      for (int r = 0; r < 16; r++) {
        int rowl = (r & 3) + 8 * (r >> 2) + 4 * q;
        int rowg = rowBase + wr * 64 + rb * 32 + rowl;
        int chg = chBase + wcl * 64 + cb * 32 + n;
        float v = acc[rb][cb][r];
        if (chg < 512) Aw[rowg * 512 + chg] = v;
        else Cw[rowg * 512 + chg - 512] = v;
      }
}

// ---------------- kernel 2: pair kernel (f16, symmetric, depth-2 pipeline) --
// Symmetric P -> triangular tiles (272), dual epilogue, atomic ch-half combine.
// Interleaved u/v k-chunks; packed-f16 formation; THREE B buffers with depth-2
// async prefetch and fine s_waitcnt vmcnt(16) (only the last phase drains to 0)
// -> prefetched loads stay in flight across barriers.
#define EI_OFF 0             // 8 rows x 520 f16 (1040B) = 8320
#define EJ_OFF 8320          // 16 rows x 1040B = 16640 -> 24960
#define BB_OFF 24960         // 3 x 16384 -> 74112
#define AJB_OFF 24960        // epilogue alias over B buf0 (16*256*4 = 16KB)
#define CJB_OFF 41344        // epilogue alias over B buf1 (16KB)
#define W2S_OFF 74112        // 1024 -> 75136
#define RED_OFF 0            // epilogue alias over dead e-tiles (4608)
#define RED2_OFF 4608        // 4608 -> 9216 (< 24960, e-region)
#define SMEM2 75136

#define WAIT16_BARRIER asm volatile("s_waitcnt vmcnt(16)\n\ts_barrier" ::: "memory")
#define WAIT0_BARRIER asm volatile("s_waitcnt vmcnt(0)\n\ts_barrier" ::: "memory")

// acc[2][4]=128 AGPR + ~120 arch VGPR <= 256: 2 waves/SIMD structural max.
__global__ __launch_bounds__(256, 2) void k_pair(
    const u16* __restrict__ E16, const u16* __restrict__ WT,
    const float* __restrict__ Aw, const float* __restrict__ Cw,
    const float* __restrict__ b1, const float* __restrict__ w2,
    const float* __restrict__ b2, float* __restrict__ out) {
  __shared__ __align__(16) char smem[SMEM2];
  const int tid = threadIdx.x;
  const int lane = tid & 63, wid = tid >> 6;
  const int wr = wid >> 1, wcl = wid & 1;
  const int n = lane & 31, q = lane >> 5;
  const int bb = blockIdx.z;
  const int ch0 = blockIdx.y * 256;

  // invert triangular tile index: f = tj*(tj+1) + ti, ti in [0, 2*tj+2)
  int f = blockIdx.x;
  int tj = (int)((__builtin_sqrtf(4.0f * (float)f + 1.0f) - 1.0f) * 0.5f);
  while ((tj + 1) * (tj + 2) <= f) tj++;
  while (tj * (tj + 1) > f) tj--;
  const int ti = f - tj * (tj + 1);
  const int bi0 = ti * 8;
  const int bj0 = tj * 16;

  // loop-invariant per-lane prefetch offset: row = wid*64 + t*16 + (lane>>2),
  // swizzle pg = (lane&3) ^ ((row>>1)&3) reduces to (lane&3)^((lane>>3)&3)
  // (t,wid parts vanish mod 4). Global elem off = (ch0+row)*2048 + col0 + pg*8.
  const int pg = (lane & 3) ^ ((lane >> 3) & 3);
  const int vInv = (wid * 64 + (lane >> 2)) * 2048 + pg * 8;  // lane-dep, loop-inv

  // async-stage B tile lk into buf nbuf; k-col = 1024 + (lk>>1)*32 + (lk&1)*512
  auto prefetch_B = [&](int lk, int nbuf) {
    const int sOff = ch0 * 2048 + 1024 + ((lk >> 1) << 5) + ((lk & 1) << 9);
    const u16* g = WT + sOff + vInv;
    char* dstBase = smem + BB_OFF + nbuf * 16384 + wid * 4096;
#pragma unroll
    for (int t = 0; t < 4; t++)
      __builtin_amdgcn_global_load_lds(
          (const __attribute__((address_space(1))) void*)(g + t * 32768),
          (__attribute__((address_space(3))) void*)(dstBase + t * 1024), 16, 0, 0);
  };

  prefetch_B(0, 0);

  // stage e-tiles f16 (rows 0..7 = e_i, 8..23 = e_j), 520-elem stride
  for (int s = tid; s < 1536; s += 256) {
    int row = s >> 6, c16 = s & 63;
    int grow = (row < 8) ? (bi0 + row) : (bj0 + row - 8);
    const u16* src = E16 + (bb * 256 + grow) * 512 + c16 * 8;
    int off = (row < 8) ? (EI_OFF + (row * 520 + c16 * 8) * 2)
                        : (EJ_OFF + ((row - 8) * 520 + c16 * 8) * 2);
    *(uint4*)(smem + off) = *(const uint4*)src;
  }
  __syncthreads();  // e-tiles visible; drains everything incl. prefetch(0)
  prefetch_B(1, 1);

  const u16* eip = (const u16*)(smem + EI_OFF) + (wr * 4 + (n >> 4)) * 520;
  const u16* ejp = (const u16*)(smem + EJ_OFF) + (n & 15) * 520;

  f32x16 acc[2][4];
  for (int a = 0; a < 2; a++)
    for (int c = 0; c < 4; c++)
      for (int e = 0; e < 16; e++) acc[a][c][e] = 0.f;

  f16x8 afv[2][2];  // held v-fragments [ks][rb]
  for (int m = 0; m < 16; m++) {
    const int dBase = m * 32;
    // ---- u-phase: tile lk=2m in buf (2m)%3 ----
    WAIT16_BARRIER;  // drains tile 2m (oldest 16 of 32 outstanding)
    if (m < 15) prefetch_B(2 * m + 2, (2 * m + 2) % 3);
    {
      const char* B2 = smem + BB_OFF + ((2 * m) % 3) * 16384;
#pragma unroll
      for (int ks = 0; ks < 2; ks++) {
        const int d0 = dBase + ks * 16 + q * 8;
        f16x8 eb = *(const f16x8*)(ejp + d0);
        f16x8 afu[2];
#pragma unroll
        for (int rb = 0; rb < 2; rb++) {
          f16x8 ea = *(const f16x8*)(eip + rb * 1040 + d0);  // 2 rows x 520
          f16x8 u = ea * eb;                                  // v_pk_mul_f16
          f16x8 dd = ea - eb;
          f16x8 vv = __builtin_elementwise_max(dd, -dd);      // v_pk_max_f16
          afu[rb] = u;
          afv[ks][rb] = vv;
        }
        const int kg = ks * 2 + q;
        f16x8 bfr[4];
#pragma unroll
        for (int cb = 0; cb < 4; cb++) {
          int ch = wcl * 128 + cb * 32 + n;
          bfr[cb] = *(const f16x8*)(B2 + ch * 64 + ((kg ^ ((ch >> 1) & 3)) * 16));
        }
#pragma unroll
        for (int rb = 0; rb < 2; rb++)
#pragma unroll
          for (int cb = 0; cb < 4; cb++)
            acc[rb][cb] = __builtin_amdgcn_mfma_f32_32x32x16_f16(
                afu[rb], bfr[cb], acc[rb][cb], 0, 0, 0);
      }
    }
    // ---- v-phase: tile lk=2m+1 in buf (2m+1)%3; pure bfr->MFMA burst ----
    if (m == 15) { WAIT0_BARRIER; } else { WAIT16_BARRIER; }
    if (m < 15) prefetch_B(2 * m + 3, (2 * m + 3) % 3);
    {
      const char* B2 = smem + BB_OFF + ((2 * m + 1) % 3) * 16384;
#pragma unroll
      for (int ks = 0; ks < 2; ks++) {
        const int kg = ks * 2 + q;
        f16x8 bfr[4];
#pragma unroll
        for (int cb = 0; cb < 4; cb++) {
          int ch = wcl * 128 + cb * 32 + n;
          bfr[cb] = *(const f16x8*)(B2 + ch * 64 + ((kg ^ ((ch >> 1) & 3)) * 16));
        }
#pragma unroll
        for (int rb = 0; rb < 2; rb++)
#pragma unroll
          for (int cb = 0; cb < 4; cb++)
            acc[rb][cb] = __builtin_amdgcn_mfma_f32_32x32x16_f16(
                afv[ks][rb], bfr[cb], acc[rb][cb], 0, 0, 0);
      }
    }
  }

  // ---- epilogue: emit fwd (i,j) and transposed (j,i) partial scores ----
  __syncthreads();  // all waves done with all B buffers and e-tiles
  {
    float b1v = b1[ch0 + tid];
    for (int j = 0; j < 16; j++) {
      int grow = (bb * 256 + bj0 + j) * 512 + ch0 + tid;
      *(float*)(smem + CJB_OFF + (j * 256 + tid) * 4) = Cw[grow] + b1v;
      *(float*)(smem + AJB_OFF + (j * 256 + tid) * 4) = Aw[grow] + b1v;
    }
    *(float*)(smem + W2S_OFF + tid * 4) = w2[ch0 + tid];
  }
  __syncthreads();

  float* RED = (float*)(smem + RED_OFF);
  float* RED2 = (float*)(smem + RED2_OFF);
  const float* CJB = (const float*)(smem + CJB_OFF);
  const float* AJB = (const float*)(smem + AJB_OFF);
  const float* W2S = (const float*)(smem + W2S_OFF);
  for (int rb = 0; rb < 2; rb++) {
    float av[4][2], civ[4][2], w2v[4];
    int chls[4];
    for (int cb = 0; cb < 4; cb++) {
      int chl = wcl * 128 + cb * 32 + n;
      chls[cb] = chl;
      w2v[cb] = W2S[chl];
      int irow = (bb * 256 + bi0 + wr * 4 + rb * 2) * 512 + ch0 + chl;
      av[cb][0] = Aw[irow];
      av[cb][1] = Aw[irow + 512];
      civ[cb][0] = Cw[irow];
      civ[cb][1] = Cw[irow + 512];
    }
    for (int r = 0; r < 16; r++) {
      int rowl = (r & 3) + 8 * (r >> 2) + 4 * q;  // C/D layout (m74/m101)
      int j = rowl & 15;
      int hi = r >> 3;
      float vf = 0.f, vt = 0.f;
      for (int cb = 0; cb < 4; cb++) {
        float base = acc[rb][cb][r];
        float hf = base + av[cb][hi] + CJB[j * 256 + chls[cb]];
        if (hf > 0.f) vf += hf * w2v[cb];
        float ht = base + civ[cb][hi] + AJB[j * 256 + chls[cb]];
        if (ht > 0.f) vt += ht * w2v[cb];
      }
      vf += __shfl_xor(vf, 1); vt += __shfl_xor(vt, 1);
      vf += __shfl_xor(vf, 2); vt += __shfl_xor(vt, 2);
      vf += __shfl_xor(vf, 4); vt += __shfl_xor(vt, 4);
      if ((n & 7) == 0) {
        int p = wr * 64 + rb * 32 + rowl;
        int slot = p * 9 + wcl * 4 + (n >> 3);
        RED[slot] = vf;
        RED2[slot] = vt;
      }
    }
  }

  __syncthreads();
  {
    int p = tid & 127;
    int gi = bi0 + (p >> 4), gj = bj0 + (p & 15);
    float half_b2 = 0.5f * b2[0];  // each ch-half block contributes half of b2
    if (tid < 128) {
      float s = half_b2;
      for (int u = 0; u < 8; u++) s += RED[p * 9 + u];
      if (gi <= gj) atomicAdd(out + (bb * 256 + gi) * 256 + gj, s);
    } else {
      float s = half_b2;
      for (int u = 0; u < 8; u++) s += RED2[p * 9 + u];
      if (gi < gj) atomicAdd(out + (bb * 256 + gj) * 256 + gi, s);
    }
  }
}

// ---------------- launcher ----------------
extern "C" void kernel_launch(void* const* d_in, const int* in_sizes, int n_in,
                              void* d_out, int out_size, void* d_ws, size_t ws_size,
                              hipStream_t stream) {
  const float* E = (const float*)d_in[0];
  const float* W1 = (const float*)d_in[1];
  const float* b1 = (const float*)d_in[2];
  const float* W2 = (const float*)d_in[3];
  const float* b2 = (const float*)d_in[4];
  float* out = (float*)d_out;
  char* ws = (char*)d_ws;
  u16* E16 = (u16*)(ws + WS_E16);
  u16* WT = (u16*)(ws + WS_WT);
  float* Aw = (float*)(ws + WS_A);
  float* Cw = (float*)(ws + WS_C);

  // k_cvt also zeroes out (atomic-combine target) — no separate memset
  hipLaunchKernelGGL(k_cvt, dim3(768), dim3(256), 0, stream, E, E16, W1, WT, out);
  hipLaunchKernelGGL(k_ac, dim3(8, 8), dim3(256), 0, stream, E16, WT, Aw, Cw);
  // 272 = # of 8x16 pair-tiles intersecting the upper triangle (tj*(tj+1)+ti)
  hipLaunchKernelGGL(k_pair, dim3(272, 2, 4), dim3(256), 0, stream,
                     E16, WT, Aw, Cw, b1, W2, b2, out);
}

// Round 11
// 260.285 us; speedup vs baseline: 1.0300x; 1.0300x over previous
//
#include <hip/hip_runtime.h>
#include <stdint.h>

typedef unsigned int u32;
typedef unsigned short u16;
typedef __attribute__((ext_vector_type(8))) _Float16 f16x8;
typedef __attribute__((ext_vector_type(16))) float f32x16;

#define DEVI __device__ __forceinline__

// ---------------- numeric helpers ----------------
DEVI u16 f2h(float f) {  // f32 -> f16 RNE (v_cvt_f16_f32)
  _Float16 h = (_Float16)f;
  return __builtin_bit_cast(u16, h);
}

// ---------------- ws layout (bytes) ----------------
#define WS_E16 0             // f16 E, [1024 rows][512]
#define WS_WT (1u << 20)     // f16 W1^T, [512 ch][2048 k]
#define WS_A (3u << 20)      // f32 a = E@Wa
#define WS_C (5u << 20)      // f32 c = E@Wb

// ---------------- kernel 0: fused E->f16 + out-zeroing (blocks 0..511) and
//                  W1 (2048x512 f32) -> W16T (512x2048 f16) (blocks 512..767)
__global__ void k_cvt(const float* __restrict__ E, u16* __restrict__ E16,
                      const float* __restrict__ W1, u16* __restrict__ WT,
                      float* __restrict__ outz) {
  __shared__ float tile[64][65];
  if (blockIdx.x < 512) {
    int i = (blockIdx.x * blockDim.x + threadIdx.x) * 4;
    float4 v = *(const float4*)(E + i);
    ushort4 o;
    o.x = f2h(v.x); o.y = f2h(v.y); o.z = f2h(v.z); o.w = f2h(v.w);
    *(ushort4*)(E16 + i) = o;
    // fold output zeroing (atomic-combine target): 256 blocks x 1024 floats
    if (blockIdx.x < 256) {
      float4 z; z.x = 0.f; z.y = 0.f; z.z = 0.f; z.w = 0.f;
      *(float4*)(outz + (blockIdx.x * blockDim.x + threadIdx.x) * 4) = z;
    }
    return;
  }
  int bid = blockIdx.x - 512;
  int t = threadIdx.x;
  int kBase = (bid & 31) * 64;   // 32 k-tiles
  int chBase = (bid >> 5) * 64;  // 8 ch-tiles
  int lr = t >> 4, lc = (t & 15) * 4;
  for (int rr = 0; rr < 4; rr++) {
    int kr = lr + rr * 16;
    float4 v = *(const float4*)(W1 + (kBase + kr) * 512 + chBase + lc);
    tile[kr][lc] = v.x; tile[kr][lc + 1] = v.y;
    tile[kr][lc + 2] = v.z; tile[kr][lc + 3] = v.w;
  }
  __syncthreads();
  int ch = t >> 2, ks = (t & 3) * 16;
  u32 w[8];
  for (int u = 0; u < 8; u++) {
    u16 lo = f2h(tile[ks + 2 * u][ch]);
    u16 hi = f2h(tile[ks + 2 * u + 1][ch]);
    w[u] = (u32)lo | ((u32)hi << 16);
  }
  u16* dst = WT + (chBase + ch) * 2048 + kBase + ks;
  uint4 s0; s0.x = w[0]; s0.y = w[1]; s0.z = w[2]; s0.w = w[3];
  uint4 s1; s1.x = w[4]; s1.y = w[5]; s1.z = w[6]; s1.w = w[7];
  *(uint4*)(dst) = s0;
  *(uint4*)(dst + 8) = s1;
}

// ---------------- kernel 1: a = E@Wa, c = E@Wb (f16 MFMA) -------------------
// Retiled 64x64 (R10: 128x128 grid 8x8 = 64 blocks -> only 25% of CUs busy).
// grid 16x16 = 256 blocks, 8KB LDS, acc 16 AGPR/wave. K-chunk order identical
// to the 128-tile version -> bitwise-identical Aw/Cw.
__global__ __launch_bounds__(256) void k_ac(const u16* __restrict__ E16,
                                            const u16* __restrict__ WT,
                                            float* __restrict__ Aw,
                                            float* __restrict__ Cw) {
  __shared__ __align__(16) char smem[8192];
  char* sA = smem;         // [64 rows][32 k] f16, swizzled
  char* sB = smem + 4096;  // [64 ch][32 k]
  const int tid = threadIdx.x;
  const int lane = tid & 63, wid = tid >> 6;
  const int wr2 = wid >> 1, wc2 = wid & 1;  // wave quadrant of the 64x64 tile
  const int n = lane & 31, q = lane >> 5;
  const int rowBase = blockIdx.y * 64;
  const int chBase = blockIdx.x * 64;
  const int halfOff = (chBase >= 512) ? 512 : 0;
  const int chSrc0 = chBase - halfOff;
  f32x16 acc;
  for (int e = 0; e < 16; e++) acc[e] = 0.f;
  const int srow = tid >> 2, spg = tid & 3;
  const int slg = spg ^ ((srow >> 1) & 3);
  for (int kc = 0; kc < 16; kc++) {
    const int k0 = kc * 32;
    __syncthreads();
    *(uint4*)(sA + srow * 64 + slg * 16) =
        *(const uint4*)(E16 + (rowBase + srow) * 512 + k0 + spg * 8);
    *(uint4*)(sB + srow * 64 + slg * 16) =
        *(const uint4*)(WT + (chSrc0 + srow) * 2048 + halfOff + k0 + spg * 8);
    __syncthreads();
    for (int ks = 0; ks < 2; ks++) {
      int kg = ks * 2 + q;
      int row = wr2 * 32 + n;
      int ch = wc2 * 32 + n;
      f16x8 af = *(const f16x8*)(sA + row * 64 + ((kg ^ ((row >> 1) & 3)) * 16));
      f16x8 bf = *(const f16x8*)(sB + ch * 64 + ((kg ^ ((ch >> 1) & 3)) * 16));
      acc = __builtin_amdgcn_mfma_f32_32x32x16_f16(af, bf, acc, 0, 0, 0);
    }
  }
  for (int r = 0; r < 16; r++) {
    int rowl = (r & 3) + 8 * (r >> 2) + 4 * q;  // C/D layout (m74/m101)
    int rowg = rowBase + wr2 * 32 + rowl;
    int chg = chBase + wc2 * 32 + n;
    float v = acc[r];
    if (chg < 512) Aw[rowg * 512 + chg] = v;
    else Cw[rowg * 512 + chg - 512] = v;
  }
}

// ---------------- kernel 2: pair kernel (f16, symmetric, depth-2 pipeline) --
// Symmetric P -> triangular tiles (272), dual epilogue, atomic ch-half combine.
// Interleaved u/v k-chunks; packed-f16 formation; THREE B buffers with depth-2
// async prefetch. vmcnt is PER-WAVE INSTRUCTION count: each prefetch_B = 4
// global_load_lds per wave, so draining the consumed tile while keeping the
// next in flight is s_waitcnt vmcnt(4) (R10's vmcnt(16) never waited -> race).
#define EI_OFF 0             // 8 rows x 520 f16 (1040B) = 8320
#define EJ_OFF 8320          // 16 rows x 1040B = 16640 -> 24960
#define BB_OFF 24960         // 3 x 16384 -> 74112
#define AJB_OFF 24960        // epilogue alias over B buf0 (16*256*4 = 16KB)
#define CJB_OFF 41344        // epilogue alias over B buf1 (16KB)
#define W2S_OFF 74112        // 1024 -> 75136
#define RED_OFF 0            // epilogue alias over dead e-tiles (4608)
#define RED2_OFF 4608        // 4608 -> 9216 (< 24960, e-region)
#define SMEM2 75136

#define WAIT4_BARRIER asm volatile("s_waitcnt vmcnt(4)\n\ts_barrier" ::: "memory")
#define WAIT0_BARRIER asm volatile("s_waitcnt vmcnt(0)\n\ts_barrier" ::: "memory")

// acc[2][4]=128 AGPR + ~120 arch VGPR <= 256: 2 waves/SIMD structural max.
__global__ __launch_bounds__(256, 2) void k_pair(
    const u16* __restrict__ E16, const u16* __restrict__ WT,
    const float* __restrict__ Aw, const float* __restrict__ Cw,
    const float* __restrict__ b1, const float* __restrict__ w2,
    const float* __restrict__ b2, float* __restrict__ out) {
  __shared__ __align__(16) char smem[SMEM2];
  const int tid = threadIdx.x;
  const int lane = tid & 63, wid = tid >> 6;
  const int wr = wid >> 1, wcl = wid & 1;
  const int n = lane & 31, q = lane >> 5;
  const int bb = blockIdx.z;
  const int ch0 = blockIdx.y * 256;

  // invert triangular tile index: f = tj*(tj+1) + ti, ti in [0, 2*tj+2)
  int f = blockIdx.x;
  int tj = (int)((__builtin_sqrtf(4.0f * (float)f + 1.0f) - 1.0f) * 0.5f);
  while ((tj + 1) * (tj + 2) <= f) tj++;
  while (tj * (tj + 1) > f) tj--;
  const int ti = f - tj * (tj + 1);
  const int bi0 = ti * 8;
  const int bj0 = tj * 16;

  // loop-invariant per-lane prefetch offset (R10-verified identical addresses)
  const int pg = (lane & 3) ^ ((lane >> 3) & 3);
  const int vInv = (wid * 64 + (lane >> 2)) * 2048 + pg * 8;

  // async-stage B tile lk into buf nbuf; k-col = 1024 + (lk>>1)*32 + (lk&1)*512
  auto prefetch_B = [&](int lk, int nbuf) {
    const int sOff = ch0 * 2048 + 1024 + ((lk >> 1) << 5) + ((lk & 1) << 9);
    const u16* g = WT + sOff + vInv;
    char* dstBase = smem + BB_OFF + nbuf * 16384 + wid * 4096;
#pragma unroll
    for (int t = 0; t < 4; t++)
      __builtin_amdgcn_global_load_lds(
          (const __attribute__((address_space(1))) void*)(g + t * 32768),
          (__attribute__((address_space(3))) void*)(dstBase + t * 1024), 16, 0, 0);
  };

  prefetch_B(0, 0);

  // stage e-tiles f16 (rows 0..7 = e_i, 8..23 = e_j), 520-elem stride
  for (int s = tid; s < 1536; s += 256) {
    int row = s >> 6, c16 = s & 63;
    int grow = (row < 8) ? (bi0 + row) : (bj0 + row - 8);
    const u16* src = E16 + (bb * 256 + grow) * 512 + c16 * 8;
    int off = (row < 8) ? (EI_OFF + (row * 520 + c16 * 8) * 2)
                        : (EJ_OFF + ((row - 8) * 520 + c16 * 8) * 2);
    *(uint4*)(smem + off) = *(const uint4*)src;
  }
  __syncthreads();  // e-tiles visible; drains everything incl. prefetch(0)
  prefetch_B(1, 1);

  const u16* eip = (const u16*)(smem + EI_OFF) + (wr * 4 + (n >> 4)) * 520;
  const u16* ejp = (const u16*)(smem + EJ_OFF) + (n & 15) * 520;

  f32x16 acc[2][4];
  for (int a = 0; a < 2; a++)
    for (int c = 0; c < 4; c++)
      for (int e = 0; e < 16; e++) acc[a][c][e] = 0.f;

  f16x8 afv[2][2];  // held v-fragments [ks][rb]
  for (int m = 0; m < 16; m++) {
    const int dBase = m * 32;
    // ---- u-phase: tile lk=2m in buf (2m)%3 ----
    WAIT4_BARRIER;  // tile 2m complete; tile 2m+1 stays in flight
    if (m < 15) prefetch_B(2 * m + 2, (2 * m + 2) % 3);
    {
      const char* B2 = smem + BB_OFF + ((2 * m) % 3) * 16384;
#pragma unroll
      for (int ks = 0; ks < 2; ks++) {
        const int d0 = dBase + ks * 16 + q * 8;
        f16x8 eb = *(const f16x8*)(ejp + d0);
        f16x8 afu[2];
#pragma unroll
        for (int rb = 0; rb < 2; rb++) {
          f16x8 ea = *(const f16x8*)(eip + rb * 1040 + d0);  // 2 rows x 520
          f16x8 u = ea * eb;                                  // v_pk_mul_f16
          f16x8 dd = ea - eb;
          f16x8 vv = __builtin_elementwise_max(dd, -dd);      // v_pk_max_f16
          afu[rb] = u;
          afv[ks][rb] = vv;
        }
        const int kg = ks * 2 + q;
        f16x8 bfr[4];
#pragma unroll
        for (int cb = 0; cb < 4; cb++) {
          int ch = wcl * 128 + cb * 32 + n;
          bfr[cb] = *(const f16x8*)(B2 + ch * 64 + ((kg ^ ((ch >> 1) & 3)) * 16));
        }
#pragma unroll
        for (int rb = 0; rb < 2; rb++)
#pragma unroll
          for (int cb = 0; cb < 4; cb++)
            acc[rb][cb] = __builtin_amdgcn_mfma_f32_32x32x16_f16(
                afu[rb], bfr[cb], acc[rb][cb], 0, 0, 0);
      }
    }
    // ---- v-phase: tile lk=2m+1 in buf (2m+1)%3; pure bfr->MFMA burst ----
    if (m == 15) { WAIT0_BARRIER; } else { WAIT4_BARRIER; }
    if (m < 15) prefetch_B(2 * m + 3, (2 * m + 3) % 3);
    {
      const char* B2 = smem + BB_OFF + ((2 * m + 1) % 3) * 16384;
#pragma unroll
      for (int ks = 0; ks < 2; ks++) {
        const int kg = ks * 2 + q;
        f16x8 bfr[4];
#pragma unroll
        for (int cb = 0; cb < 4; cb++) {
          int ch = wcl * 128 + cb * 32 + n;
          bfr[cb] = *(const f16x8*)(B2 + ch * 64 + ((kg ^ ((ch >> 1) & 3)) * 16));
        }
#pragma unroll
        for (int rb = 0; rb < 2; rb++)
#pragma unroll
          for (int cb = 0; cb < 4; cb++)
            acc[rb][cb] = __builtin_amdgcn_mfma_f32_32x32x16_f16(
                afv[ks][rb], bfr[cb], acc[rb][cb], 0, 0, 0);
      }
    }
  }

  // ---- epilogue: emit fwd (i,j) and transposed (j,i) partial scores ----
  __syncthreads();  // all waves done with all B buffers and e-tiles
  {
    float b1v = b1[ch0 + tid];
    for (int j = 0; j < 16; j++) {
      int grow = (bb * 256 + bj0 + j) * 512 + ch0 + tid;
      *(float*)(smem + CJB_OFF + (j * 256 + tid) * 4) = Cw[grow] + b1v;
      *(float*)(smem + AJB_OFF + (j * 256 + tid) * 4) = Aw[grow] + b1v;
    }
    *(float*)(smem + W2S_OFF + tid * 4) = w2[ch0 + tid];
  }
  __syncthreads();

  float* RED = (float*)(smem + RED_OFF);
  float* RED2 = (float*)(smem + RED2_OFF);
  const float* CJB = (const float*)(smem + CJB_OFF);
  const float* AJB = (const float*)(smem + AJB_OFF);
  const float* W2S = (const float*)(smem + W2S_OFF);
  for (int rb = 0; rb < 2; rb++) {
    float av[4][2], civ[4][2], w2v[4];
    int chls[4];
    for (int cb = 0; cb < 4; cb++) {
      int chl = wcl * 128 + cb * 32 + n;
      chls[cb] = chl;
      w2v[cb] = W2S[chl];
      int irow = (bb * 256 + bi0 + wr * 4 + rb * 2) * 512 + ch0 + chl;
      av[cb][0] = Aw[irow];
      av[cb][1] = Aw[irow + 512];
      civ[cb][0] = Cw[irow];
      civ[cb][1] = Cw[irow + 512];
    }
    for (int r = 0; r < 16; r++) {
      int rowl = (r & 3) + 8 * (r >> 2) + 4 * q;  // C/D layout (m74/m101)
      int j = rowl & 15;
      int hi = r >> 3;
      float vf = 0.f, vt = 0.f;
      for (int cb = 0; cb < 4; cb++) {
        float base = acc[rb][cb][r];
        float hf = base + av[cb][hi] + CJB[j * 256 + chls[cb]];
        if (hf > 0.f) vf += hf * w2v[cb];
        float ht = base + civ[cb][hi] + AJB[j * 256 + chls[cb]];
        if (ht > 0.f) vt += ht * w2v[cb];
      }
      vf += __shfl_xor(vf, 1); vt += __shfl_xor(vt, 1);
      vf += __shfl_xor(vf, 2); vt += __shfl_xor(vt, 2);
      vf += __shfl_xor(vf, 4); vt += __shfl_xor(vt, 4);
      if ((n & 7) == 0) {
        int p = wr * 64 + rb * 32 + rowl;
        int slot = p * 9 + wcl * 4 + (n >> 3);
        RED[slot] = vf;
        RED2[slot] = vt;
      }
    }
  }

  __syncthreads();
  {
    int p = tid & 127;
    int gi = bi0 + (p >> 4), gj = bj0 + (p & 15);
    float half_b2 = 0.5f * b2[0];  // each ch-half block contributes half of b2
    if (tid < 128) {
      float s = half_b2;
      for (int u = 0; u < 8; u++) s += RED[p * 9 + u];
      if (gi <= gj) atomicAdd(out + (bb * 256 + gi) * 256 + gj, s);
    } else {
      float s = half_b2;
      for (int u = 0; u < 8; u++) s += RED2[p * 9 + u];
      if (gi < gj) atomicAdd(out + (bb * 256 + gj) * 256 + gi, s);
    }
  }
}

// ---------------- launcher ----------------
extern "C" void kernel_launch(void* const* d_in, const int* in_sizes, int n_in,
                              void* d_out, int out_size, void* d_ws, size_t ws_size,
                              hipStream_t stream) {
  const float* E = (const float*)d_in[0];
  const float* W1 = (const float*)d_in[1];
  const float* b1 = (const float*)d_in[2];
  const float* W2 = (const float*)d_in[3];
  const float* b2 = (const float*)d_in[4];
  float* out = (float*)d_out;
  char* ws = (char*)d_ws;
  u16* E16 = (u16*)(ws + WS_E16);
  u16* WT = (u16*)(ws + WS_WT);
  float* Aw = (float*)(ws + WS_A);
  float* Cw = (float*)(ws + WS_C);

  // k_cvt also zeroes out (atomic-combine target) — no separate memset
  hipLaunchKernelGGL(k_cvt, dim3(768), dim3(256), 0, stream, E, E16, W1, WT, out);
  hipLaunchKernelGGL(k_ac, dim3(16, 16), dim3(256), 0, stream, E16, WT, Aw, Cw);
  // 272 = # of 8x16 pair-tiles intersecting the upper triangle (tj*(tj+1)+ti)
  hipLaunchKernelGGL(k_pair, dim3(272, 2, 4), dim3(256), 0, stream,
                     E16, WT, Aw, Cw, b1, W2, b2, out);
}